// Round 6
// baseline (273.872 us; speedup 1.0000x reference)
//
#include <hip/hip_runtime.h>
#include <stdint.h>

#define D_MODEL 1024
#define NH      16
#define BB      4
#define TT      2048
#define MROWS   (BB * TT)   // 8192

typedef __attribute__((ext_vector_type(8))) short bf16x8;
typedef __attribute__((ext_vector_type(4))) short bf16x4;
typedef __attribute__((ext_vector_type(4))) float f32x4;

__device__ __forceinline__ unsigned short f2bf(float f) {
    union { float f; unsigned int u; } v; v.f = f;
    unsigned int r = v.u + 0x7fffu + ((v.u >> 16) & 1u);   // RNE
    return (unsigned short)(r >> 16);
}

__device__ __forceinline__ unsigned short f2bf_fast(float f) {   // round-half-up (2 ops)
    union { float f; unsigned int u; } v; v.f = f;
    return (unsigned short)((v.u + 0x8000u) >> 16);
}

// K=16 bf16 MFMA via inline asm (mnemonic per cdna4_isa.md §10).
// A,B = 4 bf16 (2 VGPRs, k = quad*4+j), C/D = f32x4 (16x16 family layout).
__device__ __forceinline__ f32x4 mfma_16x16x16_bf16(bf16x4 a, bf16x4 b, f32x4 c) {
    asm("v_mfma_f32_16x16x16_bf16 %0, %1, %2, %0" : "+v"(c) : "v"(a), "v"(b));
    return c;
}

__device__ __forceinline__ void gload_lds16(const unsigned short* g, unsigned short* l) {
    __builtin_amdgcn_global_load_lds(
        (const __attribute__((address_space(1))) void*)g,
        (__attribute__((address_space(3))) void*)l,
        16, 0, 0);
}

// ---------------- fused prep: weight transpose+convert (z<4) | x fp32->bf16 (z==4) ----------------
__global__ void prep_kernel(const float* __restrict__ x, unsigned short* __restrict__ xb,
                            const float* __restrict__ wq, const float* __restrict__ wk,
                            const float* __restrict__ wv, const float* __restrict__ wo,
                            unsigned short* tq, unsigned short* tk,
                            unsigned short* tv, unsigned short* to_) {
    if (blockIdx.z == 4) {
        // convert x: 1024 blocks * 256 threads * 8 float4 = 2M float4 = 8M floats
        int base = (blockIdx.y * 32 + blockIdx.x) * 2048 + threadIdx.x;
        #pragma unroll
        for (int j = 0; j < 8; ++j) {
            int i = base + j * 256;
            float4 v = ((const float4*)x)[i];
            ushort4 o;
            o.x = f2bf(v.x); o.y = f2bf(v.y); o.z = f2bf(v.z); o.w = f2bf(v.w);
            ((ushort4*)xb)[i] = o;
        }
        return;
    }
    const float* src; unsigned short* dst;
    switch (blockIdx.z) {
        case 0:  src = wq; dst = tq; break;
        case 1:  src = wk; dst = tk; break;
        case 2:  src = wv; dst = tv; break;
        default: src = wo; dst = to_; break;
    }
    __shared__ float tile[32][33];
    int tx = threadIdx.x & 31, ty = threadIdx.x >> 5;   // 32 x 8
    int k0 = blockIdx.y * 32, n0 = blockIdx.x * 32;
    #pragma unroll
    for (int i = 0; i < 4; ++i)
        tile[ty + i * 8][tx] = src[(k0 + ty + i * 8) * D_MODEL + n0 + tx];
    __syncthreads();
    #pragma unroll
    for (int i = 0; i < 4; ++i)
        dst[(n0 + ty + i * 8) * D_MODEL + k0 + tx] = f2bf(tile[tx][ty + i * 8]);
}

// ---------------- shared 128x128 GEMM mainloop, BK=64 (A[M,K] * Bt[N,K]^T) ----------------
__device__ __forceinline__ void gemm_mainloop(const unsigned short* __restrict__ A,
                                              const unsigned short* __restrict__ Bt,
                                              int m0, int n0,
                                              unsigned short* As, unsigned short* Bs,
                                              f32x4 acc[4][4]) {
    const int tid = threadIdx.x;
    const int lane = tid & 63, wave = tid >> 6;
    const int wm = (wave >> 1) * 64, wn = (wave & 1) * 64;
    const int l15 = lane & 15, quad = lane >> 4;
    const int rx7 = l15 & 7;
    const int srow = tid >> 3;                       // 0..31
    const int scol = ((tid & 7) ^ (srow & 7)) * 8;   // source chunk, XOR-swizzled
    const unsigned short* Ag = A + (size_t)(m0 + srow) * D_MODEL + scol;
    const unsigned short* Bg = Bt + (size_t)(n0 + srow) * D_MODEL + scol;
    unsigned short* AsW = As + wave * 512;           // wave-uniform LDS base
    unsigned short* BsW = Bs + wave * 512;
    for (int k0 = 0; k0 < D_MODEL; k0 += 64) {
        __syncthreads();
        #pragma unroll
        for (int p = 0; p < 4; ++p) {                // 4 row-groups of 32
            gload_lds16(Ag + k0 + (size_t)(32 * p) * D_MODEL, AsW + (32 * p) * 64);
            gload_lds16(Bg + k0 + (size_t)(32 * p) * D_MODEL, BsW + (32 * p) * 64);
        }
        __syncthreads();
        #pragma unroll
        for (int kk = 0; kk < 2; ++kk) {
            const int co = ((kk * 4 + quad) ^ rx7) * 8;
            bf16x8 af[4], bfr[4];
            #pragma unroll
            for (int mt = 0; mt < 4; ++mt)
                af[mt] = *(const bf16x8*)(As + (wm + mt * 16 + l15) * 64 + co);
            #pragma unroll
            for (int nt = 0; nt < 4; ++nt)
                bfr[nt] = *(const bf16x8*)(Bs + (wn + nt * 16 + l15) * 64 + co);
            #pragma unroll
            for (int mt = 0; mt < 4; ++mt)
                #pragma unroll
                for (int nt = 0; nt < 4; ++nt)
                    acc[mt][nt] = __builtin_amdgcn_mfma_f32_16x16x32_bf16(af[mt], bfr[nt], acc[mt][nt], 0, 0, 0);
        }
    }
}

// ---------------- fused QKV projection GEMM (N = 3072) ----------------
// R12: XCD-aware block swizzle (T1). Default x-major dispatch round-robins
// consecutive N-tiles of one M-row across the 8 XCDs -> every XCD refetches
// every A-panel (FETCH 73MB vs ~24MB ideal). Bijective remap (1536%8==0)
// gives each XCD 8 contiguous M-rows: per-XCD A traffic 16MB->2MB.
__global__ __launch_bounds__(256, 2) void gemm_qkv_kernel(
        const unsigned short* __restrict__ Xb, const unsigned short* __restrict__ Wt,
        const float* __restrict__ bq, const float* __restrict__ bk, const float* __restrict__ bv,
        unsigned short* __restrict__ Qo, unsigned short* __restrict__ Ko,
        unsigned short* __restrict__ VTo) {
    __shared__ unsigned short S[18432];   // mainloop: As=S[0:8192), Bs=S[8192:16384); epilogue: 2 x 9216 O-stage
    unsigned short* As = S;
    unsigned short* Bs = S + 8192;
    const int bid = blockIdx.y * 24 + blockIdx.x;        // dispatch order (x fastest)
    const int swz = (bid & 7) * 192 + (bid >> 3);        // XCD k -> contiguous chunk [k*192,(k+1)*192)
    int m0 = (swz / 24) * 128, n0 = (swz % 24) * 128;
    f32x4 acc[4][4];
    #pragma unroll
    for (int mt = 0; mt < 4; ++mt)
        #pragma unroll
        for (int nt = 0; nt < 4; ++nt)
            acc[mt][nt] = (f32x4){0.f, 0.f, 0.f, 0.f};
    gemm_mainloop(Xb, Wt, m0, n0, As, Bs, acc);

    const int sel = n0 >> 10;                 // 0=Q 1=K 2=V (uniform per block)
    const float* bias = (sel == 0) ? bq : (sel == 1) ? bk : bv;
    const float scale = (sel == 0) ? 0.125f * 1.44269504f : 1.f;
    const int tid = threadIdx.x, lane = tid & 63, wave = tid >> 6;
    const int wm = (wave >> 1) * 64, wn = (wave & 1) * 64, l15 = lane & 15, quad = lane >> 4;
    if (sel < 2) {
        unsigned short* Out = (sel == 0) ? Qo : Ko;
        __syncthreads();   // mainloop LDS reads done before repurposing S
        unsigned short* R = S + (wn >> 6) * 9216;   // region per head-half (stride 72)
        #pragma unroll
        for (int nt = 0; nt < 4; ++nt) {
            int ln = nt * 16 + l15;
            int col = (n0 + wn + nt * 16 + l15) & 1023;
            float bv_ = bias[col];
            #pragma unroll
            for (int mt = 0; mt < 4; ++mt)
                #pragma unroll
                for (int r = 0; r < 4; ++r) {
                    int lm = wm + mt * 16 + quad * 4 + r;
                    R[lm * 72 + ln] = f2bf((acc[mt][nt][r] + bv_) * scale);
                }
        }
        __syncthreads();
        int hh = tid >> 7, t = tid & 127;           // one full 128-B row per thread
        int h0 = (n0 & 1023) >> 6;
        int b = m0 >> 11, tb = m0 & 2047;
        unsigned short* gp = Out + (size_t)((b * NH + h0 + hh) * TT + tb + t) * 64;
        const unsigned short* lp = S + hh * 9216 + t * 72;
        #pragma unroll
        for (int j = 0; j < 8; ++j)
            *(uint4*)(gp + j * 8) = *(const uint4*)(lp + j * 8);
    } else {
        #pragma unroll
        for (int nt = 0; nt < 4; ++nt) {
            int col = (n0 + wn + nt * 16 + l15) & 1023;
            float bv_ = bias[col];
            int h = col >> 6, dd = col & 63;
            #pragma unroll
            for (int mt = 0; mt < 4; ++mt) {
                int gm0 = m0 + wm + mt * 16 + quad * 4;
                int b = gm0 >> 11, t0 = gm0 & 2047;
                ushort4 o;
                o.x = f2bf(acc[mt][nt][0] + bv_);
                o.y = f2bf(acc[mt][nt][1] + bv_);
                o.z = f2bf(acc[mt][nt][2] + bv_);
                o.w = f2bf(acc[mt][nt][3] + bv_);
                // tiled: [BH][tile=t>>7][d][t&127]
                *(ushort4*)&VTo[(((size_t)(b * NH + h) * 16 + (t0 >> 7)) * 64 + dd) * 128 + (t0 & 127)] = o;
            }
        }
    }
}

// ---------------- output projection GEMM: fp32 out + bias ----------------
// R12: XCD swizzle (512%8==0) + LDS-restaged epilogue -> full 128B-line float4
// stores (was: scalar f32 stores = 64B partial-line segments). Two 64-row
// halves through a stride-133 f32 LDS region (bank-uniform).
__global__ __launch_bounds__(256, 2) void gemm_out_kernel(
        const unsigned short* __restrict__ Ob, const unsigned short* __restrict__ Wto,
        const float* __restrict__ bo, float* __restrict__ out) {
    __shared__ unsigned short S[18432];   // mainloop 32KB; epilogue: f32 stage 64 x 133
    unsigned short* As = S;
    unsigned short* Bs = S + 8192;
    const int bid = blockIdx.y * 8 + blockIdx.x;
    const int swz = (bid & 7) * 64 + (bid >> 3);
    int m0 = (swz >> 3) * 128, n0 = (swz & 7) * 128;
    f32x4 acc[4][4];
    #pragma unroll
    for (int mt = 0; mt < 4; ++mt)
        #pragma unroll
        for (int nt = 0; nt < 4; ++nt)
            acc[mt][nt] = (f32x4){0.f, 0.f, 0.f, 0.f};
    gemm_mainloop(Ob, Wto, m0, n0, As, Bs, acc);
    const int tid = threadIdx.x, lane = tid & 63, wave = tid >> 6;
    const int wm = (wave >> 1) * 64, wn = (wave & 1) * 64, l15 = lane & 15, quad = lane >> 4;
    float* F = (float*)S;                        // 64 rows x stride 133 (8512 f32 <= 9216)
    const int wy = wave >> 1;                    // row-half owner (0: rows 0-63, 1: rows 64-127)
    #pragma unroll
    for (int h = 0; h < 2; ++h) {                // two 64-row passes: {0-31,64-95}, {32-63,96-127}
        __syncthreads();                         // F free (mainloop reads / prev store done)
        #pragma unroll
        for (int mi = 0; mi < 2; ++mi) {
            int mt = h * 2 + mi;
            #pragma unroll
            for (int nt = 0; nt < 4; ++nt) {
                int col = wn + nt * 16 + l15;    // 0..127
                float bv_ = bo[n0 + col];
                #pragma unroll
                for (int r = 0; r < 4; ++r) {
                    int slot = wy * 32 + mi * 16 + quad * 4 + r;
                    F[slot * 133 + col] = acc[mt][nt][r] + bv_;
                }
            }
        }
        __syncthreads();
        // store: 64 staged rows x 512B; thread -> 128B (8 float4)
        int slot = tid >> 2, qtr = tid & 3;
        int grow = m0 + (slot & 31) + (slot >> 5) * 64 + h * 32;
        const float* fp = F + slot * 133 + qtr * 32;
        float* gp = out + (size_t)grow * D_MODEL + n0 + qtr * 32;
        #pragma unroll
        for (int j = 0; j < 8; ++j)
            *(float4*)(gp + j * 4) = *(const float4*)(fp + j * 4);
    }
}

// ---------------- causal flash attention: PAIRED q-tiles, 512 threads ----------------
// (unchanged from R11: paired q-tiles balance block durations; shared K/V DMA;
// in-register P via swapped QK -> K=16 PV; wave-uniform diagonal skip.)
__global__ __launch_bounds__(512, 4) void flash_kernel(
        const unsigned short* __restrict__ Q, const unsigned short* __restrict__ K,
        const unsigned short* __restrict__ VT, unsigned short* __restrict__ O) {
    __shared__ unsigned short S[18432];          // 36864 B
    unsigned short* Kd = S;                      // [2][4096]: K tile dbuf, [row][c^(row&7)]
    unsigned short* Vd = S + 8192;               // [2][4096]: V^T tile dbuf, [d][c^(d&7)]
    const int n = blockIdx.x;
    const int bh = n & 63;                       // head-clustered
    const int pr = n >> 6;                       // 0..7; pr=0 (heaviest pair) dispatches first
    const int tid = threadIdx.x, lane = tid & 63, wave = tid >> 6;
    const int g = wave >> 2;                     // 0: qtA=15-pr (waves 0-3), 1: qtB=pr (waves 4-7)
    const int qt = g ? pr : (15 - pr);
    const int q0 = qt * 128;
    const int l15 = lane & 15, quad = lane >> 4;
    const int mbase = (wave & 3) * 32;           // this wave's 32 query rows within its q-tile
    const unsigned short* Qb = Q + (size_t)bh * (TT * 64) + (size_t)q0 * 64;
    const unsigned short* Kb = K + (size_t)bh * (TT * 64);
    const unsigned short* Vtb = VT + (size_t)bh * (16 * 8192);

    // per-lane DMA source offsets (swizzle on the source side; dest is lane-ordered).
    // 512 threads cover a full 8 KB tile in ONE gload issue.
    const int kr = tid >> 3, ks = tid & 7;       // row 0..63, chunk-of-8-shorts 0..7
    const int koff = kr * 64 + ((ks ^ (kr & 7)) * 8);    // K source: row stride 64
    const int voff = kr * 128 + ((ks ^ (kr & 7)) * 8);   // V^T source: row stride 128
    auto fire = [&](int kt, int buf) {
        gload_lds16(Kb + kt * 4096 + koff, Kd + buf * 4096 + wave * 512);
        gload_lds16(Vtb + (kt >> 1) * 8192 + (kt & 1) * 64 + voff, Vd + buf * 4096 + wave * 512);
    };

    // Q fragments live in registers for the whole block
    bf16x8 qf[2][2];
    #pragma unroll
    for (int mt = 0; mt < 2; ++mt)
        #pragma unroll
        for (int kk = 0; kk < 2; ++kk)
            qf[mt][kk] = *(const bf16x8*)(Qb + (size_t)(mbase + mt * 16 + l15) * 64 + kk * 32 + quad * 8);

    float l_full[2] = {0.f, 0.f};                // l-sum for q = mbase + mt*16 + l15
    f32x4 acc[2][4];
    #pragma unroll
    for (int mt = 0; mt < 2; ++mt)
        #pragma unroll
        for (int nt = 0; nt < 4; ++nt) acc[mt][nt] = (f32x4){0.f, 0.f, 0.f, 0.f};

    fire(0, 0);   // prologue DMA (drained at first barrier)

    const int nkt = 32 - 2 * pr;                 // = 2*qtA + 2 (covers both groups)
    for (int kt = 0; kt < nkt; ++kt) {
        const int p = kt & 1;
        __syncthreads();                 // drains DMA(kt) (fired a full iteration ago) + buffer-reuse sync
        if (kt + 1 < nkt) fire(kt + 1, p ^ 1);
        // wave-uniform skip: tile's first absolute key beyond this wave's last query row
        if (kt * 64 > q0 + mbase + 31) continue;
        const unsigned short* Ksl = Kd + p * 4096;
        const unsigned short* Vsl = Vd + p * 4096;

        // ---- QK (swapped: A=K, B=Q -> col=query, row=key) for BOTH slices ----
        f32x4 sf[2][2][2];   // [s4][mt][ntl]
        #pragma unroll
        for (int s4 = 0; s4 < 2; ++s4)
            #pragma unroll
            for (int mt = 0; mt < 2; ++mt)
                #pragma unroll
                for (int ntl = 0; ntl < 2; ++ntl) sf[s4][mt][ntl] = (f32x4){0.f, 0.f, 0.f, 0.f};
        __builtin_amdgcn_s_setprio(1);
        #pragma unroll
        for (int s4 = 0; s4 < 2; ++s4)
            #pragma unroll
            for (int kk = 0; kk < 2; ++kk)
                #pragma unroll
                for (int ntl = 0; ntl < 2; ++ntl) {
                    int row = s4 * 32 + ntl * 16 + l15;
                    bf16x8 kf = *(const bf16x8*)&Ksl[row * 64 + (((kk * 4 + quad) ^ (row & 7)) * 8)];
                    #pragma unroll
                    for (int mt = 0; mt < 2; ++mt)
                        sf[s4][mt][ntl] = __builtin_amdgcn_mfma_f32_16x16x32_bf16(kf, qf[mt][kk], sf[s4][mt][ntl], 0, 0, 0);
                }
        __builtin_amdgcn_s_setprio(0);
        if (kt >= 2 * qt) {   // diagonal tiles: causal mask (exp2(-1e30) -> 0)
            const int kofs = (kt - 2 * qt) * 64;
            #pragma unroll
            for (int s4 = 0; s4 < 2; ++s4)
                #pragma unroll
                for (int mt = 0; mt < 2; ++mt) {
                    int qi = mbase + mt * 16 + l15;
                    #pragma unroll
                    for (int ntl = 0; ntl < 2; ++ntl)
                        #pragma unroll
                        for (int r = 0; r < 4; ++r) {
                            int ki = kofs + s4 * 32 + ntl * 16 + quad * 4 + r;
                            if (ki > qi) sf[s4][mt][ntl][r] = -1e30f;
                        }
                }
        }
        // ---- softmax + PV, pipelined across the two slices ----
        bf16x4 pa[2][2][2];   // [s4][mt][ntl]
        #pragma unroll
        for (int s4 = 0; s4 < 2; ++s4) {
            #pragma unroll
            for (int mt = 0; mt < 2; ++mt)
                #pragma unroll
                for (int ntl = 0; ntl < 2; ++ntl) {
                    float p0 = __builtin_amdgcn_exp2f(sf[s4][mt][ntl][0]);
                    float p1 = __builtin_amdgcn_exp2f(sf[s4][mt][ntl][1]);
                    float p2 = __builtin_amdgcn_exp2f(sf[s4][mt][ntl][2]);
                    float p3 = __builtin_amdgcn_exp2f(sf[s4][mt][ntl][3]);
                    l_full[mt] += (p0 + p1) + (p2 + p3);
                    bf16x4 pk;
                    pk[0] = (short)f2bf_fast(p0);
                    pk[1] = (short)f2bf_fast(p1);
                    pk[2] = (short)f2bf_fast(p2);
                    pk[3] = (short)f2bf_fast(p3);
                    pa[s4][mt][ntl] = pk;
                }
            __builtin_amdgcn_s_setprio(1);
            #pragma unroll
            for (int ntl = 0; ntl < 2; ++ntl) {
                #pragma unroll
                for (int ntv = 0; ntv < 4; ++ntv) {
                    int d = ntv * 16 + l15;
                    int cch = s4 * 4 + ntl * 2 + (quad >> 1);   // 8-short chunk of key range
                    bf16x4 vf = *(const bf16x4*)&Vsl[d * 64 + ((cch ^ (d & 7)) * 8) + (quad & 1) * 4];
                    #pragma unroll
                    for (int mt = 0; mt < 2; ++mt)
                        acc[mt][ntv] = mfma_16x16x16_bf16(pa[s4][mt][ntl], vf, acc[mt][ntv]);
                }
            }
            __builtin_amdgcn_s_setprio(0);
        }
    }

    // ---- final l reduction: sum quads (xor 16,32), redistribute to acc-row layout ----
    const int b = bh >> 4, h = bh & 15;
    float inv[2][4];
    #pragma unroll
    for (int mt = 0; mt < 2; ++mt) {
        float l = l_full[mt];
        l += __shfl_xor(l, 16);
        l += __shfl_xor(l, 32);              // all lanes: total l for q = mbase + mt*16 + l15
        #pragma unroll
        for (int r = 0; r < 4; ++r) {
            float lr = __shfl(l, quad * 4 + r);   // l for q-row quad*4+r (held by lane with that l15)
            inv[mt][r] = __builtin_amdgcn_rcpf(lr);
        }
    }
    __syncthreads();   // all waves done with Kd/Vd before repurposing as O staging
    // O staging: group g rows at S + g*9216, stride 72 (needs 18432 shorts = full S)
    unsigned short* Ost = S + g * 9216;
    #pragma unroll
    for (int mt = 0; mt < 2; ++mt)
        #pragma unroll
        for (int nt = 0; nt < 4; ++nt)
            #pragma unroll
            for (int r = 0; r < 4; ++r)
                Ost[(mbase + mt * 16 + quad * 4 + r) * 72 + nt * 16 + l15] =
                    f2bf(acc[mt][nt][r] * inv[mt][r]);
    __syncthreads();
    {
        int row = tid >> 1, seg = tid & 1;      // 256 rows x two 32-short segments
        int gg = row >> 7, r128 = row & 127;
        int qtw = gg ? pr : (15 - pr);
        unsigned short* gp = O + (size_t)(b * TT + qtw * 128 + r128) * D_MODEL + h * 64 + seg * 32;
        const unsigned short* lp = S + gg * 9216 + r128 * 72 + seg * 32;
        #pragma unroll
        for (int j = 0; j < 4; ++j)
            *(uint4*)(gp + j * 8) = *(const uint4*)(lp + j * 8);
    }
}

extern "C" void kernel_launch(void* const* d_in, const int* in_sizes, int n_in,
                              void* d_out, int out_size, void* d_ws, size_t ws_size,
                              hipStream_t stream) {
    const float* x  = (const float*)d_in[0];
    // d_in[1] = mask (tril causal) — causality applied analytically in flash_kernel
    const float* wq = (const float*)d_in[2];
    const float* bq = (const float*)d_in[3];
    const float* wk = (const float*)d_in[4];
    const float* bk = (const float*)d_in[5];
    const float* wv = (const float*)d_in[6];
    const float* bv = (const float*)d_in[7];
    const float* wo = (const float*)d_in[8];
    const float* bo = (const float*)d_in[9];

    char* ws = (char*)d_ws;
    unsigned short* Xb  = (unsigned short*)ws;                         // 16 MB (reused as flash O)
    unsigned short* Wtq = (unsigned short*)(ws + (size_t)(16 << 20));  // 2 MB each; Q|K|V contiguous
    unsigned short* Wtk = Wtq + (size_t)D_MODEL * D_MODEL;
    unsigned short* Wtv = Wtk + (size_t)D_MODEL * D_MODEL;
    unsigned short* Wto = Wtv + (size_t)D_MODEL * D_MODEL;
    unsigned short* Qb  = Wto + (size_t)D_MODEL * D_MODEL;             // 16 MB each
    unsigned short* Kb  = Qb + (size_t)MROWS * D_MODEL;
    unsigned short* VTb = Kb + (size_t)MROWS * D_MODEL;                // tiled [BH][16][64][128]
    unsigned short* Ob  = Xb;   // alias: X dead after gemm_qkv

    prep_kernel<<<dim3(32, 32, 5), 256, 0, stream>>>(x, Xb, wq, wk, wv, wo, Wtq, Wtk, Wtv, Wto);
    gemm_qkv_kernel<<<dim3(24, MROWS / 128), 256, 0, stream>>>(
        Xb, Wtq, bq, bk, bv, Qb, Kb, VTb);
    flash_kernel<<<dim3(8 * 64), 512, 0, stream>>>(Qb, Kb, VTb, Ob);
    gemm_out_kernel<<<dim3(8, MROWS / 128), 256, 0, stream>>>(Ob, Wto, bo, (float*)d_out);
}

// Round 7
// 243.256 us; speedup vs baseline: 1.1259x; 1.1259x over previous
//
#include <hip/hip_runtime.h>
#include <stdint.h>

#define D_MODEL 1024
#define NH      16
#define BB      4
#define TT      2048
#define MROWS   (BB * TT)   // 8192

typedef __attribute__((ext_vector_type(8))) short bf16x8;
typedef __attribute__((ext_vector_type(4))) short bf16x4;
typedef __attribute__((ext_vector_type(4))) float f32x4;

__device__ __forceinline__ unsigned short f2bf(float f) {
    union { float f; unsigned int u; } v; v.f = f;
    unsigned int r = v.u + 0x7fffu + ((v.u >> 16) & 1u);   // RNE
    return (unsigned short)(r >> 16);
}

__device__ __forceinline__ unsigned short f2bf_fast(float f) {   // round-half-up (2 ops)
    union { float f; unsigned int u; } v; v.f = f;
    return (unsigned short)((v.u + 0x8000u) >> 16);
}

// K=16 bf16 MFMA via inline asm (mnemonic per cdna4_isa.md §10).
// A,B = 4 bf16 (2 VGPRs, k = quad*4+j), C/D = f32x4 (16x16 family layout).
__device__ __forceinline__ f32x4 mfma_16x16x16_bf16(bf16x4 a, bf16x4 b, f32x4 c) {
    asm("v_mfma_f32_16x16x16_bf16 %0, %1, %2, %0" : "+v"(c) : "v"(a), "v"(b));
    return c;
}

__device__ __forceinline__ void gload_lds16(const unsigned short* g, unsigned short* l) {
    __builtin_amdgcn_global_load_lds(
        (const __attribute__((address_space(1))) void*)g,
        (__attribute__((address_space(3))) void*)l,
        16, 0, 0);
}

// ---------------- fused prep: weight transpose+convert (z<4) | x fp32->bf16 (z==4) ----------------
__global__ void prep_kernel(const float* __restrict__ x, unsigned short* __restrict__ xb,
                            const float* __restrict__ wq, const float* __restrict__ wk,
                            const float* __restrict__ wv, const float* __restrict__ wo,
                            unsigned short* tq, unsigned short* tk,
                            unsigned short* tv, unsigned short* to_) {
    if (blockIdx.z == 4) {
        // convert x: 1024 blocks * 256 threads * 8 float4 = 2M float4 = 8M floats
        int base = (blockIdx.y * 32 + blockIdx.x) * 2048 + threadIdx.x;
        #pragma unroll
        for (int j = 0; j < 8; ++j) {
            int i = base + j * 256;
            float4 v = ((const float4*)x)[i];
            ushort4 o;
            o.x = f2bf(v.x); o.y = f2bf(v.y); o.z = f2bf(v.z); o.w = f2bf(v.w);
            ((ushort4*)xb)[i] = o;
        }
        return;
    }
    const float* src; unsigned short* dst;
    switch (blockIdx.z) {
        case 0:  src = wq; dst = tq; break;
        case 1:  src = wk; dst = tk; break;
        case 2:  src = wv; dst = tv; break;
        default: src = wo; dst = to_; break;
    }
    __shared__ float tile[32][33];
    int tx = threadIdx.x & 31, ty = threadIdx.x >> 5;   // 32 x 8
    int k0 = blockIdx.y * 32, n0 = blockIdx.x * 32;
    #pragma unroll
    for (int i = 0; i < 4; ++i)
        tile[ty + i * 8][tx] = src[(k0 + ty + i * 8) * D_MODEL + n0 + tx];
    __syncthreads();
    #pragma unroll
    for (int i = 0; i < 4; ++i)
        dst[(n0 + ty + i * 8) * D_MODEL + k0 + tx] = f2bf(tile[tx][ty + i * 8]);
}

// ---------------- shared 128x128 GEMM mainloop, BK=64 (A[M,K] * Bt[N,K]^T) ----------------
__device__ __forceinline__ void gemm_mainloop(const unsigned short* __restrict__ A,
                                              const unsigned short* __restrict__ Bt,
                                              int m0, int n0,
                                              unsigned short* As, unsigned short* Bs,
                                              f32x4 acc[4][4]) {
    const int tid = threadIdx.x;
    const int lane = tid & 63, wave = tid >> 6;
    const int wm = (wave >> 1) * 64, wn = (wave & 1) * 64;
    const int l15 = lane & 15, quad = lane >> 4;
    const int rx7 = l15 & 7;
    const int srow = tid >> 3;                       // 0..31
    const int scol = ((tid & 7) ^ (srow & 7)) * 8;   // source chunk, XOR-swizzled
    const unsigned short* Ag = A + (size_t)(m0 + srow) * D_MODEL + scol;
    const unsigned short* Bg = Bt + (size_t)(n0 + srow) * D_MODEL + scol;
    unsigned short* AsW = As + wave * 512;           // wave-uniform LDS base
    unsigned short* BsW = Bs + wave * 512;
    for (int k0 = 0; k0 < D_MODEL; k0 += 64) {
        __syncthreads();
        #pragma unroll
        for (int p = 0; p < 4; ++p) {                // 4 row-groups of 32
            gload_lds16(Ag + k0 + (size_t)(32 * p) * D_MODEL, AsW + (32 * p) * 64);
            gload_lds16(Bg + k0 + (size_t)(32 * p) * D_MODEL, BsW + (32 * p) * 64);
        }
        __syncthreads();
        #pragma unroll
        for (int kk = 0; kk < 2; ++kk) {
            const int co = ((kk * 4 + quad) ^ rx7) * 8;
            bf16x8 af[4], bfr[4];
            #pragma unroll
            for (int mt = 0; mt < 4; ++mt)
                af[mt] = *(const bf16x8*)(As + (wm + mt * 16 + l15) * 64 + co);
            #pragma unroll
            for (int nt = 0; nt < 4; ++nt)
                bfr[nt] = *(const bf16x8*)(Bs + (wn + nt * 16 + l15) * 64 + co);
            #pragma unroll
            for (int mt = 0; mt < 4; ++mt)
                #pragma unroll
                for (int nt = 0; nt < 4; ++nt)
                    acc[mt][nt] = __builtin_amdgcn_mfma_f32_16x16x32_bf16(af[mt], bfr[nt], acc[mt][nt], 0, 0, 0);
        }
    }
}

// ---------------- fused QKV projection GEMM (N = 3072) ----------------
// (R12's XCD swizzle REVERTED: it raised FETCH 73->79MB — the assumed bid->XCD
// mapping was wrong, remap destroyed natural A-panel temporal locality.)
__global__ __launch_bounds__(256, 2) void gemm_qkv_kernel(
        const unsigned short* __restrict__ Xb, const unsigned short* __restrict__ Wt,
        const float* __restrict__ bq, const float* __restrict__ bk, const float* __restrict__ bv,
        unsigned short* __restrict__ Qo, unsigned short* __restrict__ Ko,
        unsigned short* __restrict__ VTo) {
    __shared__ unsigned short S[18432];   // mainloop: As=S[0:8192), Bs=S[8192:16384); epilogue: 2 x 9216 O-stage
    unsigned short* As = S;
    unsigned short* Bs = S + 8192;
    int m0 = blockIdx.y * 128, n0 = blockIdx.x * 128;
    f32x4 acc[4][4];
    #pragma unroll
    for (int mt = 0; mt < 4; ++mt)
        #pragma unroll
        for (int nt = 0; nt < 4; ++nt)
            acc[mt][nt] = (f32x4){0.f, 0.f, 0.f, 0.f};
    gemm_mainloop(Xb, Wt, m0, n0, As, Bs, acc);

    const int sel = n0 >> 10;                 // 0=Q 1=K 2=V (uniform per block)
    const float* bias = (sel == 0) ? bq : (sel == 1) ? bk : bv;
    const float scale = (sel == 0) ? 0.125f * 1.44269504f : 1.f;
    const int tid = threadIdx.x, lane = tid & 63, wave = tid >> 6;
    const int wm = (wave >> 1) * 64, wn = (wave & 1) * 64, l15 = lane & 15, quad = lane >> 4;
    if (sel < 2) {
        unsigned short* Out = (sel == 0) ? Qo : Ko;
        __syncthreads();   // mainloop LDS reads done before repurposing S
        unsigned short* R = S + (wn >> 6) * 9216;   // region per head-half (stride 72)
        #pragma unroll
        for (int nt = 0; nt < 4; ++nt) {
            int ln = nt * 16 + l15;
            int col = (n0 + wn + nt * 16 + l15) & 1023;
            float bv_ = bias[col];
            #pragma unroll
            for (int mt = 0; mt < 4; ++mt)
                #pragma unroll
                for (int r = 0; r < 4; ++r) {
                    int lm = wm + mt * 16 + quad * 4 + r;
                    R[lm * 72 + ln] = f2bf((acc[mt][nt][r] + bv_) * scale);
                }
        }
        __syncthreads();
        int hh = tid >> 7, t = tid & 127;           // one full 128-B row per thread
        int h0 = (n0 & 1023) >> 6;
        int b = m0 >> 11, tb = m0 & 2047;
        unsigned short* gp = Out + (size_t)((b * NH + h0 + hh) * TT + tb + t) * 64;
        const unsigned short* lp = S + hh * 9216 + t * 72;
        #pragma unroll
        for (int j = 0; j < 8; ++j)
            *(uint4*)(gp + j * 8) = *(const uint4*)(lp + j * 8);
    } else {
        #pragma unroll
        for (int nt = 0; nt < 4; ++nt) {
            int col = (n0 + wn + nt * 16 + l15) & 1023;
            float bv_ = bias[col];
            int h = col >> 6, dd = col & 63;
            #pragma unroll
            for (int mt = 0; mt < 4; ++mt) {
                int gm0 = m0 + wm + mt * 16 + quad * 4;
                int b = gm0 >> 11, t0 = gm0 & 2047;
                ushort4 o;
                o.x = f2bf(acc[mt][nt][0] + bv_);
                o.y = f2bf(acc[mt][nt][1] + bv_);
                o.z = f2bf(acc[mt][nt][2] + bv_);
                o.w = f2bf(acc[mt][nt][3] + bv_);
                // tiled: [BH][tile=t>>7][d][t&127]
                *(ushort4*)&VTo[(((size_t)(b * NH + h) * 16 + (t0 >> 7)) * 64 + dd) * 128 + (t0 & 127)] = o;
            }
        }
    }
}

// ---------------- output projection GEMM: fp32 out + bias (reverted to R11 epilogue) ----------------
__global__ __launch_bounds__(256, 2) void gemm_out_kernel(
        const unsigned short* __restrict__ Ob, const unsigned short* __restrict__ Wto,
        const float* __restrict__ bo, float* __restrict__ out) {
    __shared__ unsigned short As[128 * 64], Bs[128 * 64];
    int m0 = blockIdx.y * 128, n0 = blockIdx.x * 128;
    f32x4 acc[4][4];
    #pragma unroll
    for (int mt = 0; mt < 4; ++mt)
        #pragma unroll
        for (int nt = 0; nt < 4; ++nt)
            acc[mt][nt] = (f32x4){0.f, 0.f, 0.f, 0.f};
    gemm_mainloop(Ob, Wto, m0, n0, As, Bs, acc);
    const int tid = threadIdx.x, lane = tid & 63, wave = tid >> 6;
    const int wm = (wave >> 1) * 64, wn = (wave & 1) * 64, l15 = lane & 15, quad = lane >> 4;
    #pragma unroll
    for (int nt = 0; nt < 4; ++nt) {
        int gn = n0 + wn + nt * 16 + l15;
        float bv_ = bo[gn];
        #pragma unroll
        for (int mt = 0; mt < 4; ++mt) {
            #pragma unroll
            for (int r = 0; r < 4; ++r) {
                int gm = m0 + wm + mt * 16 + quad * 4 + r;
                out[(size_t)gm * D_MODEL + gn] = acc[mt][nt][r] + bv_;
            }
        }
    }
}

// ---------------- causal flash attention: PAIRED q-tiles, 512 threads ----------------
// R13: l-sum moved from VALU to matrix pipe. l[q] = sum_k P[q][k] is computed
// by 8 extra K=16 MFMAs/tile with B=ones (pipe is 33%-idle), replacing 24
// serial f32 adds in the exp2->pack critical path AND the 6-shuffle final
// redistribution: the l-MFMA's D layout (row = quad*4+r = q) is exactly the
// acc-row layout the normalize needs. Normalizing by the sum of the SAME
// bf16-rounded P used in PV also makes rows sum exactly to 1.
__global__ __launch_bounds__(512, 4) void flash_kernel(
        const unsigned short* __restrict__ Q, const unsigned short* __restrict__ K,
        const unsigned short* __restrict__ VT, unsigned short* __restrict__ O) {
    __shared__ unsigned short S[18432];          // 36864 B
    unsigned short* Kd = S;                      // [2][4096]: K tile dbuf, [row][c^(row&7)]
    unsigned short* Vd = S + 8192;               // [2][4096]: V^T tile dbuf, [d][c^(d&7)]
    const int n = blockIdx.x;
    const int bh = n & 63;                       // head-clustered
    const int pr = n >> 6;                       // 0..7; pr=0 (heaviest pair) dispatches first
    const int tid = threadIdx.x, lane = tid & 63, wave = tid >> 6;
    const int g = wave >> 2;                     // 0: qtA=15-pr (waves 0-3), 1: qtB=pr (waves 4-7)
    const int qt = g ? pr : (15 - pr);
    const int q0 = qt * 128;
    const int l15 = lane & 15, quad = lane >> 4;
    const int mbase = (wave & 3) * 32;           // this wave's 32 query rows within its q-tile
    const unsigned short* Qb = Q + (size_t)bh * (TT * 64) + (size_t)q0 * 64;
    const unsigned short* Kb = K + (size_t)bh * (TT * 64);
    const unsigned short* Vtb = VT + (size_t)bh * (16 * 8192);

    // per-lane DMA source offsets (swizzle on the source side; dest is lane-ordered).
    // 512 threads cover a full 8 KB tile in ONE gload issue.
    const int kr = tid >> 3, ks = tid & 7;       // row 0..63, chunk-of-8-shorts 0..7
    const int koff = kr * 64 + ((ks ^ (kr & 7)) * 8);    // K source: row stride 64
    const int voff = kr * 128 + ((ks ^ (kr & 7)) * 8);   // V^T source: row stride 128
    auto fire = [&](int kt, int buf) {
        gload_lds16(Kb + kt * 4096 + koff, Kd + buf * 4096 + wave * 512);
        gload_lds16(Vtb + (kt >> 1) * 8192 + (kt & 1) * 64 + voff, Vd + buf * 4096 + wave * 512);
    };

    // Q fragments live in registers for the whole block
    bf16x8 qf[2][2];
    #pragma unroll
    for (int mt = 0; mt < 2; ++mt)
        #pragma unroll
        for (int kk = 0; kk < 2; ++kk)
            qf[mt][kk] = *(const bf16x8*)(Qb + (size_t)(mbase + mt * 16 + l15) * 64 + kk * 32 + quad * 8);

    bf16x4 ones;
    ones[0] = ones[1] = ones[2] = ones[3] = (short)0x3F80;   // bf16 1.0
    f32x4 acc_l[2];                              // l[q=quad*4+r] per mt (MFMA D-layout)
    f32x4 acc[2][4];
    #pragma unroll
    for (int mt = 0; mt < 2; ++mt) {
        acc_l[mt] = (f32x4){0.f, 0.f, 0.f, 0.f};
        #pragma unroll
        for (int nt = 0; nt < 4; ++nt) acc[mt][nt] = (f32x4){0.f, 0.f, 0.f, 0.f};
    }

    fire(0, 0);   // prologue DMA (drained at first barrier)

    const int nkt = 32 - 2 * pr;                 // = 2*qtA + 2 (covers both groups)
    for (int kt = 0; kt < nkt; ++kt) {
        const int p = kt & 1;
        __syncthreads();                 // drains DMA(kt) (fired a full iteration ago) + buffer-reuse sync
        if (kt + 1 < nkt) fire(kt + 1, p ^ 1);
        // wave-uniform skip: tile's first absolute key beyond this wave's last query row
        if (kt * 64 > q0 + mbase + 31) continue;
        const unsigned short* Ksl = Kd + p * 4096;
        const unsigned short* Vsl = Vd + p * 4096;

        // ---- QK (swapped: A=K, B=Q -> col=query, row=key) for BOTH slices ----
        f32x4 sf[2][2][2];   // [s4][mt][ntl]
        #pragma unroll
        for (int s4 = 0; s4 < 2; ++s4)
            #pragma unroll
            for (int mt = 0; mt < 2; ++mt)
                #pragma unroll
                for (int ntl = 0; ntl < 2; ++ntl) sf[s4][mt][ntl] = (f32x4){0.f, 0.f, 0.f, 0.f};
        __builtin_amdgcn_s_setprio(1);
        #pragma unroll
        for (int s4 = 0; s4 < 2; ++s4)
            #pragma unroll
            for (int kk = 0; kk < 2; ++kk)
                #pragma unroll
                for (int ntl = 0; ntl < 2; ++ntl) {
                    int row = s4 * 32 + ntl * 16 + l15;
                    bf16x8 kf = *(const bf16x8*)&Ksl[row * 64 + (((kk * 4 + quad) ^ (row & 7)) * 8)];
                    #pragma unroll
                    for (int mt = 0; mt < 2; ++mt)
                        sf[s4][mt][ntl] = __builtin_amdgcn_mfma_f32_16x16x32_bf16(kf, qf[mt][kk], sf[s4][mt][ntl], 0, 0, 0);
                }
        __builtin_amdgcn_s_setprio(0);
        if (kt >= 2 * qt) {   // diagonal tiles: causal mask (exp2(-1e30) -> 0)
            const int kofs = (kt - 2 * qt) * 64;
            #pragma unroll
            for (int s4 = 0; s4 < 2; ++s4)
                #pragma unroll
                for (int mt = 0; mt < 2; ++mt) {
                    int qi = mbase + mt * 16 + l15;
                    #pragma unroll
                    for (int ntl = 0; ntl < 2; ++ntl)
                        #pragma unroll
                        for (int r = 0; r < 4; ++r) {
                            int ki = kofs + s4 * 32 + ntl * 16 + quad * 4 + r;
                            if (ki > qi) sf[s4][mt][ntl][r] = -1e30f;
                        }
                }
        }
        // ---- softmax + PV, pipelined across the two slices ----
        bf16x4 pa[2][2][2];   // [s4][mt][ntl]
        #pragma unroll
        for (int s4 = 0; s4 < 2; ++s4) {
            #pragma unroll
            for (int mt = 0; mt < 2; ++mt)
                #pragma unroll
                for (int ntl = 0; ntl < 2; ++ntl) {
                    bf16x4 pk;
                    pk[0] = (short)f2bf_fast(__builtin_amdgcn_exp2f(sf[s4][mt][ntl][0]));
                    pk[1] = (short)f2bf_fast(__builtin_amdgcn_exp2f(sf[s4][mt][ntl][1]));
                    pk[2] = (short)f2bf_fast(__builtin_amdgcn_exp2f(sf[s4][mt][ntl][2]));
                    pk[3] = (short)f2bf_fast(__builtin_amdgcn_exp2f(sf[s4][mt][ntl][3]));
                    pa[s4][mt][ntl] = pk;
                }
            __builtin_amdgcn_s_setprio(1);
            #pragma unroll
            for (int ntl = 0; ntl < 2; ++ntl) {
                #pragma unroll
                for (int ntv = 0; ntv < 4; ++ntv) {
                    int d = ntv * 16 + l15;
                    int cch = s4 * 4 + ntl * 2 + (quad >> 1);   // 8-short chunk of key range
                    bf16x4 vf = *(const bf16x4*)&Vsl[d * 64 + ((cch ^ (d & 7)) * 8) + (quad & 1) * 4];
                    #pragma unroll
                    for (int mt = 0; mt < 2; ++mt)
                        acc[mt][ntv] = mfma_16x16x16_bf16(pa[s4][mt][ntl], vf, acc[mt][ntv]);
                }
                // l-sum on the matrix pipe: l[q] += sum_k P[q][k] (B = ones)
                #pragma unroll
                for (int mt = 0; mt < 2; ++mt)
                    acc_l[mt] = mfma_16x16x16_bf16(pa[s4][mt][ntl], ones, acc_l[mt]);
            }
            __builtin_amdgcn_s_setprio(0);
        }
    }

    // ---- normalize: acc_l rows are already in acc-row layout (q = quad*4+r) ----
    const int b = bh >> 4, h = bh & 15;
    float inv[2][4];
    #pragma unroll
    for (int mt = 0; mt < 2; ++mt)
        #pragma unroll
        for (int r = 0; r < 4; ++r)
            inv[mt][r] = __builtin_amdgcn_rcpf(acc_l[mt][r]);
    __syncthreads();   // all waves done with Kd/Vd before repurposing as O staging
    // O staging: group g rows at S + g*9216, stride 72 (needs 18432 shorts = full S)
    unsigned short* Ost = S + g * 9216;
    #pragma unroll
    for (int mt = 0; mt < 2; ++mt)
        #pragma unroll
        for (int nt = 0; nt < 4; ++nt)
            #pragma unroll
            for (int r = 0; r < 4; ++r)
                Ost[(mbase + mt * 16 + quad * 4 + r) * 72 + nt * 16 + l15] =
                    f2bf(acc[mt][nt][r] * inv[mt][r]);
    __syncthreads();
    {
        int row = tid >> 1, seg = tid & 1;      // 256 rows x two 32-short segments
        int gg = row >> 7, r128 = row & 127;
        int qtw = gg ? pr : (15 - pr);
        unsigned short* gp = O + (size_t)(b * TT + qtw * 128 + r128) * D_MODEL + h * 64 + seg * 32;
        const unsigned short* lp = S + gg * 9216 + r128 * 72 + seg * 32;
        #pragma unroll
        for (int j = 0; j < 4; ++j)
            *(uint4*)(gp + j * 8) = *(const uint4*)(lp + j * 8);
    }
}

extern "C" void kernel_launch(void* const* d_in, const int* in_sizes, int n_in,
                              void* d_out, int out_size, void* d_ws, size_t ws_size,
                              hipStream_t stream) {
    const float* x  = (const float*)d_in[0];
    // d_in[1] = mask (tril causal) — causality applied analytically in flash_kernel
    const float* wq = (const float*)d_in[2];
    const float* bq = (const float*)d_in[3];
    const float* wk = (const float*)d_in[4];
    const float* bk = (const float*)d_in[5];
    const float* wv = (const float*)d_in[6];
    const float* bv = (const float*)d_in[7];
    const float* wo = (const float*)d_in[8];
    const float* bo = (const float*)d_in[9];

    char* ws = (char*)d_ws;
    unsigned short* Xb  = (unsigned short*)ws;                         // 16 MB (reused as flash O)
    unsigned short* Wtq = (unsigned short*)(ws + (size_t)(16 << 20));  // 2 MB each; Q|K|V contiguous
    unsigned short* Wtk = Wtq + (size_t)D_MODEL * D_MODEL;
    unsigned short* Wtv = Wtk + (size_t)D_MODEL * D_MODEL;
    unsigned short* Wto = Wtv + (size_t)D_MODEL * D_MODEL;
    unsigned short* Qb  = Wto + (size_t)D_MODEL * D_MODEL;             // 16 MB each
    unsigned short* Kb  = Qb + (size_t)MROWS * D_MODEL;
    unsigned short* VTb = Kb + (size_t)MROWS * D_MODEL;                // tiled [BH][16][64][128]
    unsigned short* Ob  = Xb;   // alias: X dead after gemm_qkv

    prep_kernel<<<dim3(32, 32, 5), 256, 0, stream>>>(x, Xb, wq, wk, wv, wo, Wtq, Wtk, Wtv, Wto);
    gemm_qkv_kernel<<<dim3(3 * D_MODEL / 128, MROWS / 128), 256, 0, stream>>>(
        Xb, Wtq, bq, bk, bv, Qb, Kb, VTb);
    flash_kernel<<<dim3(8 * 64), 512, 0, stream>>>(Qb, Kb, VTb, Ob);
    gemm_out_kernel<<<dim3(D_MODEL / 128, MROWS / 128), 256, 0, stream>>>(Ob, Wto, bo, (float*)d_out);
}